// Round 6
// baseline (9248.095 us; speedup 1.0000x reference)
//
#include <hip/hip_runtime.h>
#include <hip/hip_fp16.h>

#define AS1 __attribute__((address_space(1)))
#define AS3 __attribute__((address_space(3)))

typedef _Float16 f16x8 __attribute__((ext_vector_type(8)));
typedef float f32x4 __attribute__((ext_vector_type(4)));

constexpr int NROWS = 16384;
constexpr int DIM   = 1024;
constexpr int KCENT = 12288;
constexpr int NCLS  = 4096;
constexpr int BM = 128, BN = 128, BK = 32;
constexpr int KSTEPS = DIM / BK;      // 32
constexpr int STATS_T = KCENT / 64;   // 192 stat tiles (64 cols each)

// ---------- kernel P: build label-sorted permutation (single block, deterministic) ----------
__launch_bounds__(256)
__global__ void build_perm(const int* __restrict__ lab, int* __restrict__ iperm,
                           ushort* __restrict__ segstart) {
  __shared__ ushort slab[KCENT];        // 24 KB
  __shared__ unsigned scnt[NCLS];       // 16 KB (counts, then cursors)
  __shared__ unsigned sstart[NCLS + 1]; // 16 KB
  __shared__ unsigned redw[4];
  const int tid = threadIdx.x;
  const int lane = tid & 63, wv = tid >> 6;

  for (int i = tid; i < KCENT; i += 256) slab[i] = (ushort)lab[i];
  for (int i = tid; i < NCLS; i += 256) scnt[i] = 0u;
  __syncthreads();
  for (int i = tid; i < KCENT; i += 256) atomicAdd(&scnt[slab[i]], 1u);
  __syncthreads();

  // exclusive scan over 4096 counts: 16 per thread
  unsigned loc = 0;
#pragma unroll
  for (int j = 0; j < 16; ++j) loc += scnt[tid * 16 + j];
  unsigned sc = loc;
#pragma unroll
  for (int off = 1; off < 64; off <<= 1) {
    unsigned v = __shfl_up(sc, off, 64);
    if (lane >= off) sc += v;
  }
  if (lane == 63) redw[wv] = sc;
  __syncthreads();
  unsigned wbase = 0;
  for (int w = 0; w < wv; ++w) wbase += redw[w];
  unsigned run = wbase + sc - loc;
#pragma unroll
  for (int j = 0; j < 16; ++j) {
    sstart[tid * 16 + j] = run;
    run += scnt[tid * 16 + j];
  }
  if (tid == 255) sstart[NCLS] = run;  // == KCENT
  __syncthreads();

  for (int i = tid; i < NCLS; i += 256) scnt[i] = sstart[i];
  __syncthreads();
  for (int i = tid; i < KCENT; i += 256) {
    unsigned pos = atomicAdd(&scnt[slab[i]], 1u);
    iperm[pos] = i;
  }
  __syncthreads();
  // deterministic within-class order: ascending original index (segments avg 3 long)
  for (int c = tid; c < NCLS; c += 256) {
    int a = (int)sstart[c], b = (int)sstart[c + 1];
    for (int i = a + 1; i < b; ++i) {
      int v = iperm[i], j = i - 1;
      while (j >= a && iperm[j] > v) { iperm[j + 1] = iperm[j]; --j; }
      iperm[j + 1] = v;
    }
  }
  for (int i = tid; i <= NCLS; i += 256) segstart[i] = (ushort)sstart[i];
}

// ---------- kernel 0a: fp32 X -> (hi, lo) fp16 split (one-sided Ootomo) ----------
__global__ void split_convert_f16(const float4* __restrict__ src,
                                  ushort4* __restrict__ hi, ushort4* __restrict__ lo, int n4) {
  int i = blockIdx.x * blockDim.x + threadIdx.x;
  if (i >= n4) return;
  float4 v = src[i];
  float a[4] = {v.x, v.y, v.z, v.w};
  unsigned short hs[4], ls[4];
#pragma unroll
  for (int j = 0; j < 4; ++j) {
    _Float16 h = (_Float16)a[j];                 // v_cvt_f16_f32 (RNE)
    _Float16 l = (_Float16)(a[j] - (float)h);    // residual, ~2^-12 relative
    hs[j] = __builtin_bit_cast(unsigned short, h);
    ls[j] = __builtin_bit_cast(unsigned short, l);
  }
  hi[i] = make_ushort4(hs[0], hs[1], hs[2], hs[3]);
  lo[i] = make_ushort4(ls[0], ls[1], ls[2], ls[3]);
}

// ---------- kernel 0b: centroids fp32 -> single fp16, label-sorted row permutation ----------
__launch_bounds__(256)
__global__ void convert_perm_f16(const float4* __restrict__ src, const int* __restrict__ iperm,
                                 ushort4* __restrict__ dst) {
  const int p = blockIdx.x;               // permuted (dst) row
  const int srow = iperm[p];
  const int t = threadIdx.x;              // 256 threads x float4 = 1024 floats
  float4 v = src[(size_t)srow * (DIM / 4) + t];
  unsigned short hs[4];
  float a[4] = {v.x, v.y, v.z, v.w};
#pragma unroll
  for (int j = 0; j < 4; ++j) hs[j] = __builtin_bit_cast(unsigned short, (_Float16)a[j]);
  dst[(size_t)p * (DIM / 4) + t] = make_ushort4(hs[0], hs[1], hs[2], hs[3]);
}

// ---------- kernel 1: fp16 split GEMM (2 MFMA/frag) + per-tile softmax stats epilogue ----------
// LDS tile [128][32] fp16 (64-B rows), XOR-swizzled both-sides (see round-5 comment):
// staging keeps linear LDS dest, pre-permutes the per-lane GLOBAL source slot; ds_read
// applies the same XOR. Conflicts measured 0 at this layout.
__launch_bounds__(256, 6)
__global__ void gemm_softmax(const _Float16* __restrict__ Xh, const _Float16* __restrict__ Xl,
                             const _Float16* __restrict__ Cf,
                             _Float16* __restrict__ expo, float2* __restrict__ stats,
                             int row0) {
  __shared__ _Float16 sAh[BM * BK], sAl[BM * BK], sB[BM * BK];  // 24 KB
  const int tid  = threadIdx.x;
  const int lane = tid & 63;
  const int wv   = tid >> 6;
  const int wr   = wv >> 1, wc = wv & 1;   // 2x2 wave grid, each wave owns 64x64
  const int bm = blockIdx.x, bn = blockIdx.y;
  const size_t arow0 = (size_t)row0 + (size_t)bm * BM;
  const size_t brow0 = (size_t)bn * BN;
  const int lbase = bm * BM;

  f32x4 acc[4][4] = {};

  // staging: lane covers row r = iss*16 + (lane>>2), LDS slot lane&3 (linear dest);
  // swizzled source slot = (lane&3) ^ ((r>>1)&3) = (lane&3) ^ ((lane>>3)&3)
  const int srow = lane >> 2;
  const int scol = (((lane & 3) ^ ((lane >> 3) & 3)) * 8);

  for (int ks = 0; ks < KSTEPS; ++ks) {
    __syncthreads();
    const int kcol = ks * BK;
#pragma unroll
    for (int s = 0; s < 2; ++s) {
      const int iss = wv * 2 + s;
      const int r = iss * 16 + srow;
      const size_t ga = (arow0 + (size_t)r) * DIM + kcol + scol;
      const size_t gb = (brow0 + (size_t)r) * DIM + kcol + scol;
      const int lo_off = iss * 512;
      __builtin_amdgcn_global_load_lds((const AS1 void*)(Xh + ga), (AS3 void*)(sAh + lo_off), 16, 0, 0);
      __builtin_amdgcn_global_load_lds((const AS1 void*)(Xl + ga), (AS3 void*)(sAl + lo_off), 16, 0, 0);
      __builtin_amdgcn_global_load_lds((const AS1 void*)(Cf + gb), (AS3 void*)(sB  + lo_off), 16, 0, 0);
    }
    __syncthreads();

    f16x8 ah[4], al[4], bf[4];
    // fragment read: global k-slot g = lane>>4 of row ar; LDS slot = g ^ ((lane>>1)&3)
    const int kk = (((lane >> 4) ^ ((lane >> 1) & 3)) * 8);
    const int rsel = lane & 15;
#pragma unroll
    for (int m = 0; m < 4; ++m) {
      const int ar = wr * 64 + m * 16 + rsel;
      ah[m] = *(const f16x8*)(sAh + ar * BK + kk);
      al[m] = *(const f16x8*)(sAl + ar * BK + kk);
      const int br = wc * 64 + m * 16 + rsel;
      bf[m] = *(const f16x8*)(sB + br * BK + kk);
    }
#pragma unroll
    for (int m = 0; m < 4; ++m)
#pragma unroll
      for (int n = 0; n < 4; ++n) {
        acc[m][n] = __builtin_amdgcn_mfma_f32_16x16x32_f16(ah[m], bf[n], acc[m][n], 0, 0, 0);
        acc[m][n] = __builtin_amdgcn_mfma_f32_16x16x32_f16(al[m], bf[n], acc[m][n], 0, 0, 0);
      }
  }

  // epilogue: C/D layout col = lane&15, row = (lane>>4)*4 + reg  [m89-verified]
  const int g  = lane >> 4;
  const int cl = lane & 15;
  const int tileIdx = bn * 2 + wc;
#pragma unroll
  for (int m = 0; m < 4; ++m) {
#pragma unroll
    for (int j = 0; j < 4; ++j) {
      const int lrow = lbase + wr * 64 + m * 16 + g * 4 + j;
      float v0 = acc[m][0][j], v1 = acc[m][1][j], v2 = acc[m][2][j], v3 = acc[m][3][j];
      float mx = fmaxf(fmaxf(v0, v1), fmaxf(v2, v3));
#pragma unroll
      for (int s2 = 1; s2 < 16; s2 <<= 1) mx = fmaxf(mx, __shfl_xor(mx, s2, 64));
      float p0 = __expf(v0 - mx), p1 = __expf(v1 - mx), p2 = __expf(v2 - mx), p3 = __expf(v3 - mx);
      float sm = p0 + p1 + p2 + p3;
#pragma unroll
      for (int s2 = 1; s2 < 16; s2 <<= 1) sm += __shfl_xor(sm, s2, 64);
      _Float16* ep = expo + (size_t)lrow * KCENT + brow0 + wc * 64;
      ep[ 0 + cl] = (_Float16)p0;
      ep[16 + cl] = (_Float16)p1;
      ep[32 + cl] = (_Float16)p2;
      ep[48 + cl] = (_Float16)p3;
      if (cl == 0) stats[(size_t)lrow * STATS_T + tileIdx] = make_float2(mx, sm);
    }
  }
}

// ---------- kernel 2: combine stats + segmented sum over label-sorted columns ----------
__launch_bounds__(256)
__global__ void scatter_classes(const _Float16* __restrict__ expo, const float2* __restrict__ stats,
                                const ushort* __restrict__ segstart, float* __restrict__ out,
                                int row0) {
  __shared__ __align__(16) _Float16 srow[KCENT];  // 24 KB
  __shared__ __align__(16) float souts[NCLS];     // 16 KB
  __shared__ ushort ss[NCLS + 1];                 // 8.2 KB
  __shared__ float cf[STATS_T];
  __shared__ float red[8];
  const int row = blockIdx.x;
  const int tid = threadIdx.x;
  const int lane = tid & 63, wv = tid >> 6;

  const uint4* ep8 = (const uint4*)(expo + (size_t)row * KCENT);
  uint4* sr8 = (uint4*)srow;
#pragma unroll
  for (int i = 0; i < 6; ++i) sr8[i * 256 + tid] = ep8[i * 256 + tid];
  for (int i = tid; i <= NCLS; i += 256) ss[i] = segstart[i];

  float mt = -3.4e38f, zt = 0.f;
  if (tid < STATS_T) {
    float2 s0 = stats[(size_t)row * STATS_T + tid];
    mt = s0.x; zt = s0.y;
  }
  float m = mt;
#pragma unroll
  for (int s2 = 1; s2 < 64; s2 <<= 1) m = fmaxf(m, __shfl_xor(m, s2, 64));
  if (lane == 0) red[wv] = m;
  __syncthreads();
  m = fmaxf(fmaxf(red[0], red[1]), fmaxf(red[2], red[3]));
  float e = (tid < STATS_T) ? __expf(mt - m) : 0.f;
  float z = zt * e;
#pragma unroll
  for (int s2 = 1; s2 < 64; s2 <<= 1) z += __shfl_xor(z, s2, 64);
  if (lane == 0) red[4 + wv] = z;
  __syncthreads();
  z = (red[4] + red[5]) + (red[6] + red[7]);
  if (tid < STATS_T) cf[tid] = e / z;
  __syncthreads();

#pragma unroll
  for (int j = 0; j < 16; ++j) {
    const int c = tid + j * 256;
    const int a = ss[c], b = ss[c + 1];
    float s = 0.f;
    for (int k = a; k < b; ++k) s += (float)srow[k] * cf[k >> 6];
    souts[c] = s;
  }
  __syncthreads();

  float4* orow = (float4*)(out + (size_t)(row0 + row) * NCLS);
  const float4* o4 = (const float4*)souts;
#pragma unroll
  for (int i = 0; i < 4; ++i) orow[i * 256 + tid] = o4[i * 256 + tid];
}

extern "C" void kernel_launch(void* const* d_in, const int* in_sizes, int n_in,
                              void* d_out, int out_size, void* d_ws, size_t ws_size,
                              hipStream_t stream) {
  (void)in_sizes; (void)n_in; (void)out_size;
  const float* X = (const float*)d_in[0];
  const float* C = (const float*)d_in[1];
  const int* labels = (const int*)d_in[2];
  float* out = (float*)d_out;

  char* ws = (char*)d_ws;
  size_t off = 0;
  auto carve = [&](size_t bytes) -> char* {
    char* p = ws + off;
    off += (bytes + 255) & ~(size_t)255;
    return p;
  };
  _Float16* Xh = (_Float16*)carve((size_t)NROWS * DIM * 2);
  _Float16* Xl = (_Float16*)carve((size_t)NROWS * DIM * 2);
  _Float16* Cf = (_Float16*)carve((size_t)KCENT * DIM * 2);
  int* iperm = (int*)carve((size_t)KCENT * 4);
  ushort* segstart = (ushort*)carve((size_t)(NCLS + 1) * 2);
  const size_t fixed = off;

  const size_t per_row = (size_t)KCENT * 2 + (size_t)STATS_T * 8;
  size_t avail = (ws_size > fixed + 4096) ? (ws_size - fixed - 4096) : 0;
  long Rmax = (long)(avail / per_row);
  Rmax = (Rmax / 128) * 128;
  if (Rmax < 128) Rmax = 128;
  if (Rmax > NROWS) Rmax = NROWS;
  _Float16* expo = (_Float16*)carve((size_t)Rmax * KCENT * 2);
  float2* stats  = (float2*)carve((size_t)Rmax * STATS_T * 8);

  build_perm<<<1, 256, 0, stream>>>(labels, iperm, segstart);
  {
    int n4x = NROWS * DIM / 4;
    split_convert_f16<<<(n4x + 255) / 256, 256, 0, stream>>>((const float4*)X, (ushort4*)Xh, (ushort4*)Xl, n4x);
    convert_perm_f16<<<KCENT, 256, 0, stream>>>((const float4*)C, iperm, (ushort4*)Cf);
  }

  for (int r0 = 0; r0 < NROWS; r0 += (int)Rmax) {
    int R = (NROWS - r0 < (int)Rmax) ? (NROWS - r0) : (int)Rmax;
    dim3 grid(R / BM, KCENT / BN);
    gemm_softmax<<<grid, 256, 0, stream>>>(Xh, Xl, Cf, expo, stats, r0);
    scatter_classes<<<R, 256, 0, stream>>>(expo, stats, segstart, out, r0);
  }
}

// Round 7
// 1501.096 us; speedup vs baseline: 6.1609x; 6.1609x over previous
//
#include <hip/hip_runtime.h>
#include <hip/hip_fp16.h>

#define AS1 __attribute__((address_space(1)))
#define AS3 __attribute__((address_space(3)))

typedef _Float16 f16x8 __attribute__((ext_vector_type(8)));
typedef float f32x4 __attribute__((ext_vector_type(4)));

constexpr int NROWS = 16384;
constexpr int DIM   = 1024;
constexpr int KCENT = 12288;
constexpr int NCLS  = 4096;
constexpr int BM = 128, BN = 128, BK = 32;
constexpr int KSTEPS = DIM / BK;      // 32
constexpr int STATS_T = KCENT / 64;   // 192 stat tiles (64 cols each)

// ---------- kernel P: build label-sorted permutation (single block, deterministic) ----------
__launch_bounds__(256)
__global__ void build_perm(const int* __restrict__ lab, int* __restrict__ iperm,
                           ushort* __restrict__ segstart) {
  __shared__ ushort slab[KCENT];        // 24 KB
  __shared__ unsigned scnt[NCLS];       // 16 KB (counts, then cursors)
  __shared__ unsigned sstart[NCLS + 1]; // 16 KB
  __shared__ unsigned redw[4];
  const int tid = threadIdx.x;
  const int lane = tid & 63, wv = tid >> 6;

  for (int i = tid; i < KCENT; i += 256) slab[i] = (ushort)lab[i];
  for (int i = tid; i < NCLS; i += 256) scnt[i] = 0u;
  __syncthreads();
  for (int i = tid; i < KCENT; i += 256) atomicAdd(&scnt[slab[i]], 1u);
  __syncthreads();

  // exclusive scan over 4096 counts: 16 per thread
  unsigned loc = 0;
#pragma unroll
  for (int j = 0; j < 16; ++j) loc += scnt[tid * 16 + j];
  unsigned sc = loc;
#pragma unroll
  for (int off = 1; off < 64; off <<= 1) {
    unsigned v = __shfl_up(sc, off, 64);
    if (lane >= off) sc += v;
  }
  if (lane == 63) redw[wv] = sc;
  __syncthreads();
  unsigned wbase = 0;
  for (int w = 0; w < wv; ++w) wbase += redw[w];
  unsigned run = wbase + sc - loc;
#pragma unroll
  for (int j = 0; j < 16; ++j) {
    sstart[tid * 16 + j] = run;
    run += scnt[tid * 16 + j];
  }
  if (tid == 255) sstart[NCLS] = run;  // == KCENT
  __syncthreads();

  for (int i = tid; i < NCLS; i += 256) scnt[i] = sstart[i];
  __syncthreads();
  for (int i = tid; i < KCENT; i += 256) {
    unsigned pos = atomicAdd(&scnt[slab[i]], 1u);
    iperm[pos] = i;
  }
  __syncthreads();
  // deterministic within-class order: ascending original index (segments avg 3 long)
  for (int c = tid; c < NCLS; c += 256) {
    int a = (int)sstart[c], b = (int)sstart[c + 1];
    for (int i = a + 1; i < b; ++i) {
      int v = iperm[i], j = i - 1;
      while (j >= a && iperm[j] > v) { iperm[j + 1] = iperm[j]; --j; }
      iperm[j + 1] = v;
    }
  }
  for (int i = tid; i <= NCLS; i += 256) segstart[i] = (ushort)sstart[i];
}

// ---------- kernel 0a: fp32 X -> (hi, lo) fp16 split (one-sided Ootomo) ----------
__global__ void split_convert_f16(const float4* __restrict__ src,
                                  ushort4* __restrict__ hi, ushort4* __restrict__ lo, int n4) {
  int i = blockIdx.x * blockDim.x + threadIdx.x;
  if (i >= n4) return;
  float4 v = src[i];
  float a[4] = {v.x, v.y, v.z, v.w};
  unsigned short hs[4], ls[4];
#pragma unroll
  for (int j = 0; j < 4; ++j) {
    _Float16 h = (_Float16)a[j];                 // v_cvt_f16_f32 (RNE)
    _Float16 l = (_Float16)(a[j] - (float)h);    // residual, ~2^-12 relative
    hs[j] = __builtin_bit_cast(unsigned short, h);
    ls[j] = __builtin_bit_cast(unsigned short, l);
  }
  hi[i] = make_ushort4(hs[0], hs[1], hs[2], hs[3]);
  lo[i] = make_ushort4(ls[0], ls[1], ls[2], ls[3]);
}

// ---------- kernel 0b: centroids fp32 -> single fp16, label-sorted row permutation ----------
__launch_bounds__(256)
__global__ void convert_perm_f16(const float4* __restrict__ src, const int* __restrict__ iperm,
                                 ushort4* __restrict__ dst) {
  const int p = blockIdx.x;               // permuted (dst) row
  const int srow = iperm[p];
  const int t = threadIdx.x;              // 256 threads x float4 = 1024 floats
  float4 v = src[(size_t)srow * (DIM / 4) + t];
  unsigned short hs[4];
  float a[4] = {v.x, v.y, v.z, v.w};
#pragma unroll
  for (int j = 0; j < 4; ++j) hs[j] = __builtin_bit_cast(unsigned short, (_Float16)a[j]);
  dst[(size_t)p * (DIM / 4) + t] = make_ushort4(hs[0], hs[1], hs[2], hs[3]);
}

// ---------- kernel 1: fp16 split GEMM (2 MFMA/frag) + per-tile softmax stats epilogue ----------
// LDS tile [128][32] fp16 (64-B rows), XOR-swizzled both-sides (round-5-verified: conflicts=0):
// staging keeps linear LDS dest, pre-permutes the per-lane GLOBAL source slot; ds_read
// applies the same XOR.
// launch_bounds(256,4): unified VGPR+AGPR budget 128/wave — exactly fits 64 AGPR acc +
// ~48 VGPR frags. (256,6) caps at ~85 and SPILLS ACC TO SCRATCH (round-6: 42 GB/dispatch).
__launch_bounds__(256, 4)
__global__ void gemm_softmax(const _Float16* __restrict__ Xh, const _Float16* __restrict__ Xl,
                             const _Float16* __restrict__ Cf,
                             _Float16* __restrict__ expo, float2* __restrict__ stats,
                             int row0) {
  __shared__ _Float16 sAh[BM * BK], sAl[BM * BK], sB[BM * BK];  // 24 KB
  const int tid  = threadIdx.x;
  const int lane = tid & 63;
  const int wv   = tid >> 6;
  const int wr   = wv >> 1, wc = wv & 1;   // 2x2 wave grid, each wave owns 64x64
  const int bm = blockIdx.x, bn = blockIdx.y;
  const size_t arow0 = (size_t)row0 + (size_t)bm * BM;
  const size_t brow0 = (size_t)bn * BN;
  const int lbase = bm * BM;

  f32x4 acc[4][4] = {};

  // staging: lane covers row r = iss*16 + (lane>>2), LDS slot lane&3 (linear dest);
  // swizzled source slot = (lane&3) ^ ((r>>1)&3) = (lane&3) ^ ((lane>>3)&3)
  const int srow = lane >> 2;
  const int scol = (((lane & 3) ^ ((lane >> 3) & 3)) * 8);

  for (int ks = 0; ks < KSTEPS; ++ks) {
    __syncthreads();
    const int kcol = ks * BK;
#pragma unroll
    for (int s = 0; s < 2; ++s) {
      const int iss = wv * 2 + s;
      const int r = iss * 16 + srow;
      const size_t ga = (arow0 + (size_t)r) * DIM + kcol + scol;
      const size_t gb = (brow0 + (size_t)r) * DIM + kcol + scol;
      const int lo_off = iss * 512;
      __builtin_amdgcn_global_load_lds((const AS1 void*)(Xh + ga), (AS3 void*)(sAh + lo_off), 16, 0, 0);
      __builtin_amdgcn_global_load_lds((const AS1 void*)(Xl + ga), (AS3 void*)(sAl + lo_off), 16, 0, 0);
      __builtin_amdgcn_global_load_lds((const AS1 void*)(Cf + gb), (AS3 void*)(sB  + lo_off), 16, 0, 0);
    }
    __syncthreads();

    f16x8 ah[4], al[4], bf[4];
    // fragment read: global k-slot g = lane>>4 of row ar; LDS slot = g ^ ((lane>>1)&3)
    const int kk = (((lane >> 4) ^ ((lane >> 1) & 3)) * 8);
    const int rsel = lane & 15;
#pragma unroll
    for (int m = 0; m < 4; ++m) {
      const int ar = wr * 64 + m * 16 + rsel;
      ah[m] = *(const f16x8*)(sAh + ar * BK + kk);
      al[m] = *(const f16x8*)(sAl + ar * BK + kk);
      const int br = wc * 64 + m * 16 + rsel;
      bf[m] = *(const f16x8*)(sB + br * BK + kk);
    }
#pragma unroll
    for (int m = 0; m < 4; ++m)
#pragma unroll
      for (int n = 0; n < 4; ++n) {
        acc[m][n] = __builtin_amdgcn_mfma_f32_16x16x32_f16(ah[m], bf[n], acc[m][n], 0, 0, 0);
        acc[m][n] = __builtin_amdgcn_mfma_f32_16x16x32_f16(al[m], bf[n], acc[m][n], 0, 0, 0);
      }
  }

  // epilogue: C/D layout col = lane&15, row = (lane>>4)*4 + reg  [m89-verified]
  const int g  = lane >> 4;
  const int cl = lane & 15;
  const int tileIdx = bn * 2 + wc;
#pragma unroll
  for (int m = 0; m < 4; ++m) {
#pragma unroll
    for (int j = 0; j < 4; ++j) {
      const int lrow = lbase + wr * 64 + m * 16 + g * 4 + j;
      float v0 = acc[m][0][j], v1 = acc[m][1][j], v2 = acc[m][2][j], v3 = acc[m][3][j];
      float mx = fmaxf(fmaxf(v0, v1), fmaxf(v2, v3));
#pragma unroll
      for (int s2 = 1; s2 < 16; s2 <<= 1) mx = fmaxf(mx, __shfl_xor(mx, s2, 64));
      float p0 = __expf(v0 - mx), p1 = __expf(v1 - mx), p2 = __expf(v2 - mx), p3 = __expf(v3 - mx);
      float sm = p0 + p1 + p2 + p3;
#pragma unroll
      for (int s2 = 1; s2 < 16; s2 <<= 1) sm += __shfl_xor(sm, s2, 64);
      _Float16* ep = expo + (size_t)lrow * KCENT + brow0 + wc * 64;
      ep[ 0 + cl] = (_Float16)p0;
      ep[16 + cl] = (_Float16)p1;
      ep[32 + cl] = (_Float16)p2;
      ep[48 + cl] = (_Float16)p3;
      if (cl == 0) stats[(size_t)lrow * STATS_T + tileIdx] = make_float2(mx, sm);
    }
  }
}

// ---------- kernel 2: combine stats + segmented sum over label-sorted columns ----------
__launch_bounds__(256)
__global__ void scatter_classes(const _Float16* __restrict__ expo, const float2* __restrict__ stats,
                                const ushort* __restrict__ segstart, float* __restrict__ out,
                                int row0) {
  __shared__ __align__(16) _Float16 srow[KCENT];  // 24 KB
  __shared__ __align__(16) float souts[NCLS];     // 16 KB
  __shared__ ushort ss[NCLS + 1];                 // 8.2 KB
  __shared__ float cf[STATS_T];
  __shared__ float red[8];
  const int row = blockIdx.x;
  const int tid = threadIdx.x;
  const int lane = tid & 63, wv = tid >> 6;

  const uint4* ep8 = (const uint4*)(expo + (size_t)row * KCENT);
  uint4* sr8 = (uint4*)srow;
#pragma unroll
  for (int i = 0; i < 6; ++i) sr8[i * 256 + tid] = ep8[i * 256 + tid];
  for (int i = tid; i <= NCLS; i += 256) ss[i] = segstart[i];

  float mt = -3.4e38f, zt = 0.f;
  if (tid < STATS_T) {
    float2 s0 = stats[(size_t)row * STATS_T + tid];
    mt = s0.x; zt = s0.y;
  }
  float m = mt;
#pragma unroll
  for (int s2 = 1; s2 < 64; s2 <<= 1) m = fmaxf(m, __shfl_xor(m, s2, 64));
  if (lane == 0) red[wv] = m;
  __syncthreads();
  m = fmaxf(fmaxf(red[0], red[1]), fmaxf(red[2], red[3]));
  float e = (tid < STATS_T) ? __expf(mt - m) : 0.f;
  float z = zt * e;
#pragma unroll
  for (int s2 = 1; s2 < 64; s2 <<= 1) z += __shfl_xor(z, s2, 64);
  if (lane == 0) red[4 + wv] = z;
  __syncthreads();
  z = (red[4] + red[5]) + (red[6] + red[7]);
  if (tid < STATS_T) cf[tid] = e / z;
  __syncthreads();

#pragma unroll
  for (int j = 0; j < 16; ++j) {
    const int c = tid + j * 256;
    const int a = ss[c], b = ss[c + 1];
    float s = 0.f;
    for (int k = a; k < b; ++k) s += (float)srow[k] * cf[k >> 6];
    souts[c] = s;
  }
  __syncthreads();

  float4* orow = (float4*)(out + (size_t)(row0 + row) * NCLS);
  const float4* o4 = (const float4*)souts;
#pragma unroll
  for (int i = 0; i < 4; ++i) orow[i * 256 + tid] = o4[i * 256 + tid];
}

extern "C" void kernel_launch(void* const* d_in, const int* in_sizes, int n_in,
                              void* d_out, int out_size, void* d_ws, size_t ws_size,
                              hipStream_t stream) {
  (void)in_sizes; (void)n_in; (void)out_size;
  const float* X = (const float*)d_in[0];
  const float* C = (const float*)d_in[1];
  const int* labels = (const int*)d_in[2];
  float* out = (float*)d_out;

  char* ws = (char*)d_ws;
  size_t off = 0;
  auto carve = [&](size_t bytes) -> char* {
    char* p = ws + off;
    off += (bytes + 255) & ~(size_t)255;
    return p;
  };
  _Float16* Xh = (_Float16*)carve((size_t)NROWS * DIM * 2);
  _Float16* Xl = (_Float16*)carve((size_t)NROWS * DIM * 2);
  _Float16* Cf = (_Float16*)carve((size_t)KCENT * DIM * 2);
  int* iperm = (int*)carve((size_t)KCENT * 4);
  ushort* segstart = (ushort*)carve((size_t)(NCLS + 1) * 2);
  const size_t fixed = off;

  const size_t per_row = (size_t)KCENT * 2 + (size_t)STATS_T * 8;
  size_t avail = (ws_size > fixed + 4096) ? (ws_size - fixed - 4096) : 0;
  long Rmax = (long)(avail / per_row);
  Rmax = (Rmax / 128) * 128;
  if (Rmax < 128) Rmax = 128;
  if (Rmax > NROWS) Rmax = NROWS;
  _Float16* expo = (_Float16*)carve((size_t)Rmax * KCENT * 2);
  float2* stats  = (float2*)carve((size_t)Rmax * STATS_T * 8);

  build_perm<<<1, 256, 0, stream>>>(labels, iperm, segstart);
  {
    int n4x = NROWS * DIM / 4;
    split_convert_f16<<<(n4x + 255) / 256, 256, 0, stream>>>((const float4*)X, (ushort4*)Xh, (ushort4*)Xl, n4x);
    convert_perm_f16<<<KCENT, 256, 0, stream>>>((const float4*)C, iperm, (ushort4*)Cf);
  }

  for (int r0 = 0; r0 < NROWS; r0 += (int)Rmax) {
    int R = (NROWS - r0 < (int)Rmax) ? (NROWS - r0) : (int)Rmax;
    dim3 grid(R / BM, KCENT / BN);
    gemm_softmax<<<grid, 256, 0, stream>>>(Xh, Xl, Cf, expo, stats, r0);
    scatter_classes<<<R, 256, 0, stream>>>(expo, stats, segstart, out, r0);
  }
}

// Round 8
// 1179.991 us; speedup vs baseline: 7.8374x; 1.2721x over previous
//
#include <hip/hip_runtime.h>
#include <hip/hip_fp16.h>

#define AS1 __attribute__((address_space(1)))
#define AS3 __attribute__((address_space(3)))

typedef _Float16 f16x8 __attribute__((ext_vector_type(8)));
typedef float f32x4 __attribute__((ext_vector_type(4)));

constexpr int NROWS = 16384;
constexpr int DIM   = 1024;
constexpr int KCENT = 12288;
constexpr int NCLS  = 4096;
constexpr int BM = 128, BN = 128, BK = 32;
constexpr int KSTEPS = DIM / BK;      // 32
constexpr int STATS_T = KCENT / 64;   // 192 stat tiles (64 cols each)

// ---------- kernel P: build label-sorted permutation (single block, deterministic) ----------
__launch_bounds__(256)
__global__ void build_perm(const int* __restrict__ lab, int* __restrict__ iperm,
                           ushort* __restrict__ segstart) {
  __shared__ ushort slab[KCENT];        // 24 KB
  __shared__ unsigned scnt[NCLS];       // 16 KB (counts, then cursors)
  __shared__ unsigned sstart[NCLS + 1]; // 16 KB
  __shared__ unsigned redw[4];
  const int tid = threadIdx.x;
  const int lane = tid & 63, wv = tid >> 6;

  for (int i = tid; i < KCENT; i += 256) slab[i] = (ushort)lab[i];
  for (int i = tid; i < NCLS; i += 256) scnt[i] = 0u;
  __syncthreads();
  for (int i = tid; i < KCENT; i += 256) atomicAdd(&scnt[slab[i]], 1u);
  __syncthreads();

  // exclusive scan over 4096 counts: 16 per thread
  unsigned loc = 0;
#pragma unroll
  for (int j = 0; j < 16; ++j) loc += scnt[tid * 16 + j];
  unsigned sc = loc;
#pragma unroll
  for (int off = 1; off < 64; off <<= 1) {
    unsigned v = __shfl_up(sc, off, 64);
    if (lane >= off) sc += v;
  }
  if (lane == 63) redw[wv] = sc;
  __syncthreads();
  unsigned wbase = 0;
  for (int w = 0; w < wv; ++w) wbase += redw[w];
  unsigned run = wbase + sc - loc;
#pragma unroll
  for (int j = 0; j < 16; ++j) {
    sstart[tid * 16 + j] = run;
    run += scnt[tid * 16 + j];
  }
  if (tid == 255) sstart[NCLS] = run;  // == KCENT
  __syncthreads();

  for (int i = tid; i < NCLS; i += 256) scnt[i] = sstart[i];
  __syncthreads();
  for (int i = tid; i < KCENT; i += 256) {
    unsigned pos = atomicAdd(&scnt[slab[i]], 1u);
    iperm[pos] = i;
  }
  __syncthreads();
  // deterministic within-class order: ascending original index (segments avg 3 long)
  for (int c = tid; c < NCLS; c += 256) {
    int a = (int)sstart[c], b = (int)sstart[c + 1];
    for (int i = a + 1; i < b; ++i) {
      int v = iperm[i], j = i - 1;
      while (j >= a && iperm[j] > v) { iperm[j + 1] = iperm[j]; --j; }
      iperm[j + 1] = v;
    }
  }
  for (int i = tid; i <= NCLS; i += 256) segstart[i] = (ushort)sstart[i];
}

// ---------- kernel 0a: fp32 X -> fp16 (single pass; see error budget in header comment) ----------
__global__ void convert_f16(const float4* __restrict__ src, ushort4* __restrict__ dst, int n4) {
  int i = blockIdx.x * blockDim.x + threadIdx.x;
  if (i >= n4) return;
  float4 v = src[i];
  float a[4] = {v.x, v.y, v.z, v.w};
  unsigned short hs[4];
#pragma unroll
  for (int j = 0; j < 4; ++j) hs[j] = __builtin_bit_cast(unsigned short, (_Float16)a[j]);
  dst[i] = make_ushort4(hs[0], hs[1], hs[2], hs[3]);
}

// ---------- kernel 0b: centroids fp32 -> fp16, label-sorted row permutation ----------
__launch_bounds__(256)
__global__ void convert_perm_f16(const float4* __restrict__ src, const int* __restrict__ iperm,
                                 ushort4* __restrict__ dst) {
  const int p = blockIdx.x;               // permuted (dst) row
  const int srow = iperm[p];
  const int t = threadIdx.x;              // 256 threads x float4 = 1024 floats
  float4 v = src[(size_t)srow * (DIM / 4) + t];
  unsigned short hs[4];
  float a[4] = {v.x, v.y, v.z, v.w};
#pragma unroll
  for (int j = 0; j < 4; ++j) hs[j] = __builtin_bit_cast(unsigned short, (_Float16)a[j]);
  dst[(size_t)p * (DIM / 4) + t] = make_ushort4(hs[0], hs[1], hs[2], hs[3]);
}

// ---------- kernel 1: fp16 1-pass GEMM + per-tile softmax stats epilogue ----------
// Error budget (measured anchors): expo-fp16 floor 0.0039 (r4); C-quant adds 0.0039 (r7);
// X-quant adds the same independently -> absmax ~0.010-0.012 < 0.02 threshold.
// LDS tile [128][32] fp16 (64-B rows), XOR-swizzled both-sides (r5-verified: conflicts=0).
// launch_bounds(256,4): 128 reg/wave budget = 64 AGPR acc + ~50 VGPR. (256,6) SPILLS (r6).
__launch_bounds__(256, 4)
__global__ void gemm_softmax(const _Float16* __restrict__ Xf, const _Float16* __restrict__ Cf,
                             _Float16* __restrict__ expo, float2* __restrict__ stats,
                             int row0) {
  __shared__ _Float16 sA[BM * BK], sB[BM * BK];  // 16 KB
  const int tid  = threadIdx.x;
  const int lane = tid & 63;
  const int wv   = tid >> 6;
  const int wr   = wv >> 1, wc = wv & 1;   // 2x2 wave grid, each wave owns 64x64
  const int bm = blockIdx.x, bn = blockIdx.y;
  const size_t arow0 = (size_t)row0 + (size_t)bm * BM;
  const size_t brow0 = (size_t)bn * BN;
  const int lbase = bm * BM;

  f32x4 acc[4][4] = {};

  // staging: lane covers row r = iss*16 + (lane>>2), LDS slot lane&3 (linear dest);
  // swizzled source slot = (lane&3) ^ ((r>>1)&3) = (lane&3) ^ ((lane>>3)&3)
  const int srow = lane >> 2;
  const int scol = (((lane & 3) ^ ((lane >> 3) & 3)) * 8);

  for (int ks = 0; ks < KSTEPS; ++ks) {
    __syncthreads();
    const int kcol = ks * BK;
#pragma unroll
    for (int s = 0; s < 2; ++s) {
      const int iss = wv * 2 + s;
      const int r = iss * 16 + srow;
      const size_t ga = (arow0 + (size_t)r) * DIM + kcol + scol;
      const size_t gb = (brow0 + (size_t)r) * DIM + kcol + scol;
      const int lo_off = iss * 512;
      __builtin_amdgcn_global_load_lds((const AS1 void*)(Xf + ga), (AS3 void*)(sA + lo_off), 16, 0, 0);
      __builtin_amdgcn_global_load_lds((const AS1 void*)(Cf + gb), (AS3 void*)(sB + lo_off), 16, 0, 0);
    }
    __syncthreads();

    f16x8 af[4], bf[4];
    // fragment read: global k-slot g = lane>>4 of row ar; LDS slot = g ^ ((lane>>1)&3)
    const int kk = (((lane >> 4) ^ ((lane >> 1) & 3)) * 8);
    const int rsel = lane & 15;
#pragma unroll
    for (int m = 0; m < 4; ++m) {
      const int ar = wr * 64 + m * 16 + rsel;
      af[m] = *(const f16x8*)(sA + ar * BK + kk);
      const int br = wc * 64 + m * 16 + rsel;
      bf[m] = *(const f16x8*)(sB + br * BK + kk);
    }
#pragma unroll
    for (int m = 0; m < 4; ++m)
#pragma unroll
      for (int n = 0; n < 4; ++n)
        acc[m][n] = __builtin_amdgcn_mfma_f32_16x16x32_f16(af[m], bf[n], acc[m][n], 0, 0, 0);
  }

  // epilogue: C/D layout col = lane&15, row = (lane>>4)*4 + reg  [m89-verified]
  const int g  = lane >> 4;
  const int cl = lane & 15;
  const int tileIdx = bn * 2 + wc;
#pragma unroll
  for (int m = 0; m < 4; ++m) {
#pragma unroll
    for (int j = 0; j < 4; ++j) {
      const int lrow = lbase + wr * 64 + m * 16 + g * 4 + j;
      float v0 = acc[m][0][j], v1 = acc[m][1][j], v2 = acc[m][2][j], v3 = acc[m][3][j];
      float mx = fmaxf(fmaxf(v0, v1), fmaxf(v2, v3));
#pragma unroll
      for (int s2 = 1; s2 < 16; s2 <<= 1) mx = fmaxf(mx, __shfl_xor(mx, s2, 64));
      float p0 = __expf(v0 - mx), p1 = __expf(v1 - mx), p2 = __expf(v2 - mx), p3 = __expf(v3 - mx);
      float sm = p0 + p1 + p2 + p3;
#pragma unroll
      for (int s2 = 1; s2 < 16; s2 <<= 1) sm += __shfl_xor(sm, s2, 64);
      _Float16* ep = expo + (size_t)lrow * KCENT + brow0 + wc * 64;
      ep[ 0 + cl] = (_Float16)p0;
      ep[16 + cl] = (_Float16)p1;
      ep[32 + cl] = (_Float16)p2;
      ep[48 + cl] = (_Float16)p3;
      if (cl == 0) stats[(size_t)lrow * STATS_T + tileIdx] = make_float2(mx, sm);
    }
  }
}

// ---------- kernel 2: combine stats + segmented sum over label-sorted columns ----------
__launch_bounds__(256)
__global__ void scatter_classes(const _Float16* __restrict__ expo, const float2* __restrict__ stats,
                                const ushort* __restrict__ segstart, float* __restrict__ out,
                                int row0) {
  __shared__ __align__(16) _Float16 srow[KCENT];  // 24 KB
  __shared__ __align__(16) float souts[NCLS];     // 16 KB
  __shared__ ushort ss[NCLS + 1];                 // 8.2 KB
  __shared__ float cf[STATS_T];
  __shared__ float red[8];
  const int row = blockIdx.x;
  const int tid = threadIdx.x;
  const int lane = tid & 63, wv = tid >> 6;

  const uint4* ep8 = (const uint4*)(expo + (size_t)row * KCENT);
  uint4* sr8 = (uint4*)srow;
#pragma unroll
  for (int i = 0; i < 6; ++i) sr8[i * 256 + tid] = ep8[i * 256 + tid];
  for (int i = tid; i <= NCLS; i += 256) ss[i] = segstart[i];

  float mt = -3.4e38f, zt = 0.f;
  if (tid < STATS_T) {
    float2 s0 = stats[(size_t)row * STATS_T + tid];
    mt = s0.x; zt = s0.y;
  }
  float m = mt;
#pragma unroll
  for (int s2 = 1; s2 < 64; s2 <<= 1) m = fmaxf(m, __shfl_xor(m, s2, 64));
  if (lane == 0) red[wv] = m;
  __syncthreads();
  m = fmaxf(fmaxf(red[0], red[1]), fmaxf(red[2], red[3]));
  float e = (tid < STATS_T) ? __expf(mt - m) : 0.f;
  float z = zt * e;
#pragma unroll
  for (int s2 = 1; s2 < 64; s2 <<= 1) z += __shfl_xor(z, s2, 64);
  if (lane == 0) red[4 + wv] = z;
  __syncthreads();
  z = (red[4] + red[5]) + (red[6] + red[7]);
  if (tid < STATS_T) cf[tid] = e / z;
  __syncthreads();

#pragma unroll
  for (int j = 0; j < 16; ++j) {
    const int c = tid + j * 256;
    const int a = ss[c], b = ss[c + 1];
    float s = 0.f;
    for (int k = a; k < b; ++k) s += (float)srow[k] * cf[k >> 6];
    souts[c] = s;
  }
  __syncthreads();

  float4* orow = (float4*)(out + (size_t)(row0 + row) * NCLS);
  const float4* o4 = (const float4*)souts;
#pragma unroll
  for (int i = 0; i < 4; ++i) orow[i * 256 + tid] = o4[i * 256 + tid];
}

extern "C" void kernel_launch(void* const* d_in, const int* in_sizes, int n_in,
                              void* d_out, int out_size, void* d_ws, size_t ws_size,
                              hipStream_t stream) {
  (void)in_sizes; (void)n_in; (void)out_size;
  const float* X = (const float*)d_in[0];
  const float* C = (const float*)d_in[1];
  const int* labels = (const int*)d_in[2];
  float* out = (float*)d_out;

  char* ws = (char*)d_ws;
  size_t off = 0;
  auto carve = [&](size_t bytes) -> char* {
    char* p = ws + off;
    off += (bytes + 255) & ~(size_t)255;
    return p;
  };
  _Float16* Xf = (_Float16*)carve((size_t)NROWS * DIM * 2);
  _Float16* Cf = (_Float16*)carve((size_t)KCENT * DIM * 2);
  int* iperm = (int*)carve((size_t)KCENT * 4);
  ushort* segstart = (ushort*)carve((size_t)(NCLS + 1) * 2);
  const size_t fixed = off;

  const size_t per_row = (size_t)KCENT * 2 + (size_t)STATS_T * 8;
  size_t avail = (ws_size > fixed + 4096) ? (ws_size - fixed - 4096) : 0;
  long Rmax = (long)(avail / per_row);
  Rmax = (Rmax / 128) * 128;
  if (Rmax < 128) Rmax = 128;
  if (Rmax > NROWS) Rmax = NROWS;
  _Float16* expo = (_Float16*)carve((size_t)Rmax * KCENT * 2);
  float2* stats  = (float2*)carve((size_t)Rmax * STATS_T * 8);

  build_perm<<<1, 256, 0, stream>>>(labels, iperm, segstart);
  {
    int n4x = NROWS * DIM / 4;
    convert_f16<<<(n4x + 255) / 256, 256, 0, stream>>>((const float4*)X, (ushort4*)Xf, n4x);
    convert_perm_f16<<<KCENT, 256, 0, stream>>>((const float4*)C, iperm, (ushort4*)Cf);
  }

  for (int r0 = 0; r0 < NROWS; r0 += (int)Rmax) {
    int R = (NROWS - r0 < (int)Rmax) ? (NROWS - r0) : (int)Rmax;
    dim3 grid(R / BM, KCENT / BN);
    gemm_softmax<<<grid, 256, 0, stream>>>(Xf, Cf, expo, stats, r0);
    scatter_classes<<<R, 256, 0, stream>>>(expo, stats, segstart, out, r0);
  }
}

// Round 9
// 1025.560 us; speedup vs baseline: 9.0176x; 1.1506x over previous
//
#include <hip/hip_runtime.h>
#include <hip/hip_fp16.h>

#define AS1 __attribute__((address_space(1)))
#define AS3 __attribute__((address_space(3)))

typedef _Float16 f16x8 __attribute__((ext_vector_type(8)));
typedef float f32x4 __attribute__((ext_vector_type(4)));

constexpr int NROWS = 16384;
constexpr int DIM   = 1024;
constexpr int KCENT = 12288;
constexpr int NCLS  = 4096;
constexpr int BM = 128, BN = 128, BK = 32;
constexpr int KSTEPS = DIM / BK;      // 32
constexpr int STATS_T = KCENT / 64;   // 192 stat tiles (64 cols each)

// ---------- kernel P: label-sorted permutation + per-element class map (deterministic) ----------
__launch_bounds__(256)
__global__ void build_perm(const int* __restrict__ lab, int* __restrict__ iperm,
                           ushort* __restrict__ elemclass) {
  __shared__ ushort slab[KCENT];        // 24 KB
  __shared__ unsigned scnt[NCLS];       // 16 KB (counts, then cursors)
  __shared__ unsigned sstart[NCLS + 1]; // 16 KB
  __shared__ unsigned redw[4];
  const int tid = threadIdx.x;
  const int lane = tid & 63, wv = tid >> 6;

  for (int i = tid; i < KCENT; i += 256) slab[i] = (ushort)lab[i];
  for (int i = tid; i < NCLS; i += 256) scnt[i] = 0u;
  __syncthreads();
  for (int i = tid; i < KCENT; i += 256) atomicAdd(&scnt[slab[i]], 1u);
  __syncthreads();

  // exclusive scan over 4096 counts: 16 per thread
  unsigned loc = 0;
#pragma unroll
  for (int j = 0; j < 16; ++j) loc += scnt[tid * 16 + j];
  unsigned sc = loc;
#pragma unroll
  for (int off = 1; off < 64; off <<= 1) {
    unsigned v = __shfl_up(sc, off, 64);
    if (lane >= off) sc += v;
  }
  if (lane == 63) redw[wv] = sc;
  __syncthreads();
  unsigned wbase = 0;
  for (int w = 0; w < wv; ++w) wbase += redw[w];
  unsigned run = wbase + sc - loc;
#pragma unroll
  for (int j = 0; j < 16; ++j) {
    sstart[tid * 16 + j] = run;
    run += scnt[tid * 16 + j];
  }
  if (tid == 255) sstart[NCLS] = run;  // == KCENT
  __syncthreads();

  for (int i = tid; i < NCLS; i += 256) scnt[i] = sstart[i];
  __syncthreads();
  for (int i = tid; i < KCENT; i += 256) {
    unsigned pos = atomicAdd(&scnt[slab[i]], 1u);
    iperm[pos] = i;
  }
  __syncthreads();
  // deterministic within-class order: ascending original index (keeps graph replays
  // bit-identical to launch_once -> tripwire-safe)
  for (int c = tid; c < NCLS; c += 256) {
    int a = (int)sstart[c], b = (int)sstart[c + 1];
    for (int i = a + 1; i < b; ++i) {
      int v = iperm[i], j = i - 1;
      while (j >= a && iperm[j] > v) { iperm[j + 1] = iperm[j]; --j; }
      iperm[j + 1] = v;
    }
  }
  // per-element class id in sorted order (consumed by scatter v2)
  for (int c = tid; c < NCLS; c += 256) {
    int a = (int)sstart[c], b = (int)sstart[c + 1];
    for (int i = a; i < b; ++i) elemclass[i] = (ushort)c;
  }
}

// ---------- kernel 0a: fp32 X -> fp16 ----------
__global__ void convert_f16(const float4* __restrict__ src, ushort4* __restrict__ dst, int n4) {
  int i = blockIdx.x * blockDim.x + threadIdx.x;
  if (i >= n4) return;
  float4 v = src[i];
  float a[4] = {v.x, v.y, v.z, v.w};
  unsigned short hs[4];
#pragma unroll
  for (int j = 0; j < 4; ++j) hs[j] = __builtin_bit_cast(unsigned short, (_Float16)a[j]);
  dst[i] = make_ushort4(hs[0], hs[1], hs[2], hs[3]);
}

// ---------- kernel 0b: centroids fp32 -> fp16, label-sorted row permutation ----------
__launch_bounds__(256)
__global__ void convert_perm_f16(const float4* __restrict__ src, const int* __restrict__ iperm,
                                 ushort4* __restrict__ dst) {
  const int p = blockIdx.x;               // permuted (dst) row
  const int srow = iperm[p];
  const int t = threadIdx.x;              // 256 threads x float4 = 1024 floats
  float4 v = src[(size_t)srow * (DIM / 4) + t];
  unsigned short hs[4];
  float a[4] = {v.x, v.y, v.z, v.w};
#pragma unroll
  for (int j = 0; j < 4; ++j) hs[j] = __builtin_bit_cast(unsigned short, (_Float16)a[j]);
  dst[(size_t)p * (DIM / 4) + t] = make_ushort4(hs[0], hs[1], hs[2], hs[3]);
}

// ---------- kernel 1: fp16 1-pass GEMM + per-tile softmax stats epilogue (r8-passing, unchanged) ----------
// Error budget: expo-fp16 floor 0.0039 (r4); C-quant 0.0039 (r7); +X-quant -> 0.0117 measured (r8), < 0.02.
// LDS tile [128][32] fp16, XOR-swizzled both-sides (r5: conflicts=0).
// launch_bounds(256,4): 128 reg/wave = 64 AGPR acc + ~50 VGPR. (256,6) SPILLS (r6: 42 GB/dispatch).
__launch_bounds__(256, 4)
__global__ void gemm_softmax(const _Float16* __restrict__ Xf, const _Float16* __restrict__ Cf,
                             _Float16* __restrict__ expo, float2* __restrict__ stats,
                             int row0) {
  __shared__ _Float16 sA[BM * BK], sB[BM * BK];  // 16 KB
  const int tid  = threadIdx.x;
  const int lane = tid & 63;
  const int wv   = tid >> 6;
  const int wr   = wv >> 1, wc = wv & 1;   // 2x2 wave grid, each wave owns 64x64
  const int bm = blockIdx.x, bn = blockIdx.y;
  const size_t arow0 = (size_t)row0 + (size_t)bm * BM;
  const size_t brow0 = (size_t)bn * BN;
  const int lbase = bm * BM;

  f32x4 acc[4][4] = {};

  const int srow = lane >> 2;
  const int scol = (((lane & 3) ^ ((lane >> 3) & 3)) * 8);

  for (int ks = 0; ks < KSTEPS; ++ks) {
    __syncthreads();
    const int kcol = ks * BK;
#pragma unroll
    for (int s = 0; s < 2; ++s) {
      const int iss = wv * 2 + s;
      const int r = iss * 16 + srow;
      const size_t ga = (arow0 + (size_t)r) * DIM + kcol + scol;
      const size_t gb = (brow0 + (size_t)r) * DIM + kcol + scol;
      const int lo_off = iss * 512;
      __builtin_amdgcn_global_load_lds((const AS1 void*)(Xf + ga), (AS3 void*)(sA + lo_off), 16, 0, 0);
      __builtin_amdgcn_global_load_lds((const AS1 void*)(Cf + gb), (AS3 void*)(sB + lo_off), 16, 0, 0);
    }
    __syncthreads();

    f16x8 af[4], bf[4];
    const int kk = (((lane >> 4) ^ ((lane >> 1) & 3)) * 8);
    const int rsel = lane & 15;
#pragma unroll
    for (int m = 0; m < 4; ++m) {
      const int ar = wr * 64 + m * 16 + rsel;
      af[m] = *(const f16x8*)(sA + ar * BK + kk);
      const int br = wc * 64 + m * 16 + rsel;
      bf[m] = *(const f16x8*)(sB + br * BK + kk);
    }
#pragma unroll
    for (int m = 0; m < 4; ++m)
#pragma unroll
      for (int n = 0; n < 4; ++n)
        acc[m][n] = __builtin_amdgcn_mfma_f32_16x16x32_f16(af[m], bf[n], acc[m][n], 0, 0, 0);
  }

  const int g  = lane >> 4;
  const int cl = lane & 15;
  const int tileIdx = bn * 2 + wc;
#pragma unroll
  for (int m = 0; m < 4; ++m) {
#pragma unroll
    for (int j = 0; j < 4; ++j) {
      const int lrow = lbase + wr * 64 + m * 16 + g * 4 + j;
      float v0 = acc[m][0][j], v1 = acc[m][1][j], v2 = acc[m][2][j], v3 = acc[m][3][j];
      float mx = fmaxf(fmaxf(v0, v1), fmaxf(v2, v3));
#pragma unroll
      for (int s2 = 1; s2 < 16; s2 <<= 1) mx = fmaxf(mx, __shfl_xor(mx, s2, 64));
      float p0 = __expf(v0 - mx), p1 = __expf(v1 - mx), p2 = __expf(v2 - mx), p3 = __expf(v3 - mx);
      float sm = p0 + p1 + p2 + p3;
#pragma unroll
      for (int s2 = 1; s2 < 16; s2 <<= 1) sm += __shfl_xor(sm, s2, 64);
      _Float16* ep = expo + (size_t)lrow * KCENT + brow0 + wc * 64;
      ep[ 0 + cl] = (_Float16)p0;
      ep[16 + cl] = (_Float16)p1;
      ep[32 + cl] = (_Float16)p2;
      ep[48 + cl] = (_Float16)p3;
      if (cl == 0) stats[(size_t)lrow * STATS_T + tileIdx] = make_float2(mx, sm);
    }
  }
}

// ---------- kernel 2 (v2): register-resident segmented sum, no LDS staging, no scalar loops ----------
// Thread t owns sorted elements [48t, 48t+48). Complete segments flush straight to souts;
// the <=1 boundary-spanning segment per thread pair is combined in an LDS fixup pass.
// Max segment length ~13 (Poisson(3) over 4096) << 48 -> a segment spans at most 2 threads.
// FP add order per class identical to r8 (ascending k) -> bit-identical output.
__launch_bounds__(256)
__global__ void scatter_classes(const _Float16* __restrict__ expo, const float2* __restrict__ stats,
                                const ushort* __restrict__ elemclass, float* __restrict__ out,
                                int row0) {
  __shared__ __align__(16) float souts[NCLS];     // 16 KB
  __shared__ float cf[STATS_T];
  __shared__ float red[8];
  __shared__ int   sBC[512];                      // [t]=lead class, [256+t]=trail class
  __shared__ float sBP[512];                      // lead/trail partial sums
  const int row = blockIdx.x;
  const int tid = threadIdx.x;
  const int lane = tid & 63, wv = tid >> 6;

  // issue all 12 global loads up-front (MLP); consumed after the stats combine
  const uint4* ep8 = (const uint4*)(expo + (size_t)row * KCENT);
  const uint4* ec8 = (const uint4*)elemclass;
  unsigned ew[24], lw[24];
#pragma unroll
  for (int i = 0; i < 6; ++i) {
    uint4 v = ep8[6 * tid + i];
    ew[4 * i] = v.x; ew[4 * i + 1] = v.y; ew[4 * i + 2] = v.z; ew[4 * i + 3] = v.w;
  }
#pragma unroll
  for (int i = 0; i < 6; ++i) {
    uint4 u = ec8[6 * tid + i];
    lw[4 * i] = u.x; lw[4 * i + 1] = u.y; lw[4 * i + 2] = u.z; lw[4 * i + 3] = u.w;
  }

  for (int i = tid; i < NCLS; i += 256) souts[i] = 0.f;

  // combine per-tile stats: m = max(mt), Z = sum(zt*exp(mt-m)); cf[t] = exp(mt-m)/Z
  float mt = -3.4e38f, zt = 0.f;
  if (tid < STATS_T) {
    float2 s0 = stats[(size_t)row * STATS_T + tid];
    mt = s0.x; zt = s0.y;
  }
  float m = mt;
#pragma unroll
  for (int s2 = 1; s2 < 64; s2 <<= 1) m = fmaxf(m, __shfl_xor(m, s2, 64));
  if (lane == 0) red[wv] = m;
  __syncthreads();
  m = fmaxf(fmaxf(red[0], red[1]), fmaxf(red[2], red[3]));
  float e = (tid < STATS_T) ? __expf(mt - m) : 0.f;
  float z = zt * e;
#pragma unroll
  for (int s2 = 1; s2 < 64; s2 <<= 1) z += __shfl_xor(z, s2, 64);
  if (lane == 0) red[4 + wv] = z;
  __syncthreads();
  z = (red[4] + red[5]) + (red[6] + red[7]);
  if (tid < STATS_T) cf[tid] = e / z;
  __syncthreads();   // cf ready, souts zeroed

  // per-thread run-length accumulation over 48 elements (fully unrolled, register-resident)
  const int kbase = 48 * tid;
  const int t0 = kbase >> 6;
  const float cfA = cf[t0];
  const float cfB = cf[(t0 + 1 < STATS_T) ? t0 + 1 : t0];
  const int isw = 64 - (kbase & 63);   // elements i >= isw fall in tile t0+1

  int cur = -1; float run2 = 0.f;
  int leadc = -1; float leadp = 0.f; bool first = true;
#pragma unroll
  for (int i = 0; i < 48; ++i) {
    const unsigned w = ew[i >> 1];
    const unsigned short eh = (unsigned short)((i & 1) ? (w >> 16) : (w & 0xffffu));
    const unsigned lwv = lw[i >> 1];
    const int c = (int)((i & 1) ? (lwv >> 16) : (lwv & 0xffffu));
    const float p = (float)__builtin_bit_cast(_Float16, eh) * ((i < isw) ? cfA : cfB);
    if (c != cur) {
      if (cur >= 0) {
        if (first) { leadc = cur; leadp = run2; first = false; }
        else souts[cur] = run2;
      }
      cur = c; run2 = 0.f;
    }
    run2 += p;
  }
  if (first) leadc = -1;               // single-run thread (seg >= 48: ~impossible) -> trail only
  sBC[tid] = leadc;       sBP[tid] = leadp;
  sBC[256 + tid] = cur;   sBP[256 + tid] = run2;
  __syncthreads();

  // boundary fixup: each boundary class = trail[t] (+ lead[t+1] if same class)
  {
    const int c1 = sBC[256 + tid];
    float s = sBP[256 + tid];
    if (tid < 255 && sBC[tid + 1] == c1) s += sBP[tid + 1];
    souts[c1] = s;
    const int c0 = sBC[tid];
    if (c0 >= 0 && (tid == 0 || sBC[256 + tid - 1] != c0)) souts[c0] = sBP[tid];
  }
  __syncthreads();

  float4* orow = (float4*)(out + (size_t)(row0 + row) * NCLS);
  const float4* o4 = (const float4*)souts;
#pragma unroll
  for (int i = 0; i < 4; ++i) orow[i * 256 + tid] = o4[i * 256 + tid];
}

extern "C" void kernel_launch(void* const* d_in, const int* in_sizes, int n_in,
                              void* d_out, int out_size, void* d_ws, size_t ws_size,
                              hipStream_t stream) {
  (void)in_sizes; (void)n_in; (void)out_size;
  const float* X = (const float*)d_in[0];
  const float* C = (const float*)d_in[1];
  const int* labels = (const int*)d_in[2];
  float* out = (float*)d_out;

  char* ws = (char*)d_ws;
  size_t off = 0;
  auto carve = [&](size_t bytes) -> char* {
    char* p = ws + off;
    off += (bytes + 255) & ~(size_t)255;
    return p;
  };
  _Float16* Xf = (_Float16*)carve((size_t)NROWS * DIM * 2);
  _Float16* Cf = (_Float16*)carve((size_t)KCENT * DIM * 2);
  int* iperm = (int*)carve((size_t)KCENT * 4);
  ushort* elemclass = (ushort*)carve((size_t)KCENT * 2);
  const size_t fixed = off;

  const size_t per_row = (size_t)KCENT * 2 + (size_t)STATS_T * 8;
  size_t avail = (ws_size > fixed + 4096) ? (ws_size - fixed - 4096) : 0;
  long Rmax = (long)(avail / per_row);
  Rmax = (Rmax / 128) * 128;
  if (Rmax < 128) Rmax = 128;
  if (Rmax > NROWS) Rmax = NROWS;
  _Float16* expo = (_Float16*)carve((size_t)Rmax * KCENT * 2);
  float2* stats  = (float2*)carve((size_t)Rmax * STATS_T * 8);

  build_perm<<<1, 256, 0, stream>>>(labels, iperm, elemclass);
  {
    int n4x = NROWS * DIM / 4;
    convert_f16<<<(n4x + 255) / 256, 256, 0, stream>>>((const float4*)X, (ushort4*)Xf, n4x);
    convert_perm_f16<<<KCENT, 256, 0, stream>>>((const float4*)C, iperm, (ushort4*)Cf);
  }

  for (int r0 = 0; r0 < NROWS; r0 += (int)Rmax) {
    int R = (NROWS - r0 < (int)Rmax) ? (NROWS - r0) : (int)Rmax;
    dim3 grid(R / BM, KCENT / BN);
    gemm_softmax<<<grid, 256, 0, stream>>>(Xf, Cf, expo, stats, r0);
    scatter_classes<<<R, 256, 0, stream>>>(expo, stats, elemclass, out, r0);
  }
}